// Round 18
// baseline (43.364 us; speedup 1.0000x reference)
//
#include <hip/hip_runtime.h>
#include <hip/hip_bf16.h>

#define A_N 8
#define C_N 256
#define H_N 80
#define W_N 108
#define P_N (H_N * W_N)      // 8640
#define P4_N (P_N / 4)       // 2160 float4 columns per plane
#define O_N 7
#define MH 256
#define MW 256
#define OUT_HW 256
#define TPA 34               // 64-px4 tiles per agent (34*64 = 2176 >= 2160)
#define NCG 4                // channel groups (64 ch each)

__device__ __forceinline__ float sigmoidf_(float zv) {
    return 1.0f / (1.0f + __expf(-zv));
}

// ---------------------------------------------------------------------------
// Split-K conv with 1KB-CONTIGUOUS wave loads (the one structural feature of
// every >2TB/s kernel on this chip) at r17's occupancy and load depth.
// Grid 8a x 34 tiles x 4 ch-groups = 1088 blocks x 256 thr (4 waves,
// ~4 blocks/CU = 16 waves/CU at VGPR~110). Wave wid covers channels
// cg*64 + wid + 4k (k=0..15); lane = px4 offset in the 64-px4 tile ->
// each global_load_dwordx4 reads 64 consecutive float4 = 1KB contiguous.
// 16 loads issued upfront as named regs (16KB in flight/wave).
// cm folded into FMA input: acc += w*(x+cm). Per-block partial (64 ch) ->
// part[cg]; k_finalize sums the 4 groups (7.7MB round-trip ~ 2.5us).
// ---------------------------------------------------------------------------
__launch_bounds__(256, 2)
__global__ void k_convp(const float* __restrict__ x, const float* __restrict__ masks,
                        const float* __restrict__ w, float* __restrict__ part)
{
    __shared__ float4 s_red[O_N][NCG][64];   // [o][wid][lane], 28 KB, conflict-free
    __shared__ float  s_w[512];              // this block's 64 channels x [8]
    __shared__ float  s_cm[256];             // resized mask for tile's 256 px

    const int tid  = threadIdx.x;
    const int lane = tid & 63;
    const int wid  = tid >> 6;
    const int bi   = blockIdx.x;
    const int cg   = bi & 3;
    const int t2   = bi >> 2;
    const int tile = t2 % TPA;
    const int a    = t2 / TPA;

    // ---- stage this block's 64 channels of w -> LDS [c_local][8] ----
    if (tid < 64) {
        const int c = cg * 64 + tid;
        #pragma unroll
        for (int o = 0; o < 8; ++o)
            s_w[tid * 8 + o] = (o < O_N) ? w[o * C_N + c] : 0.0f;
    }

    // ---- inline antialias resize (jax.image.resize bilinear, antialias),
    //      fixed 7x5 window, one px per thread (256 px tile) ----
    {
        const int px = tile * 256 + tid;
        const int pc = min(px, P_N - 1);
        const int oy = pc / W_N, ox = pc - oy * W_N;
        const float ksy = 256.0f / 80.0f;
        const float ksx = 256.0f / 108.0f;
        const float rky = 0.3125f;               // 80/256 exact
        const float rkx = 0.421875f;             // 108/256 exact
        const float sfy = ((float)oy + 0.5f) * ksy - 0.5f;
        const float sfx = ((float)ox + 0.5f) * ksx - 0.5f;
        const int iyS = (int)ceilf(sfy - ksy);
        const int ixS = (int)ceilf(sfx - ksx);

        float wxv[5];
        float wxs = 0.0f;
        #pragma unroll
        for (int q = 0; q < 5; ++q) {
            const int ix = ixS + q;
            float wv = fmaxf(0.0f, 1.0f - fabsf(sfx - (float)ix) * rkx);
            wv = (ix >= 0 && ix < MW) ? wv : 0.0f;
            wxv[q] = wv;
            wxs += wv;
        }
        const float* mp = masks + (size_t)a * (MH * MW);
        float acm = 0.0f, wys = 0.0f;
        #pragma unroll
        for (int r = 0; r < 7; ++r) {
            const int iy = iyS + r;
            float wy = fmaxf(0.0f, 1.0f - fabsf(sfy - (float)iy) * rky);
            wy = (iy >= 0 && iy < MH) ? wy : 0.0f;
            wys += wy;
            const float* row = mp + min(max(iy, 0), MH - 1) * MW;
            float rs = 0.0f;
            #pragma unroll
            for (int q = 0; q < 5; ++q)
                rs = fmaf(wxv[q], row[min(max(ixS + q, 0), MW - 1)], rs);
            acm = fmaf(wy, rs, acm);
        }
        s_cm[tid] = acm / (wys * wxs);
    }
    __syncthreads();

    // ---- conv: 16 channels per lane (stride 4), 1KB-contiguous wave loads,
    //      ALL 16 loads issued before any use ----
    const int px4  = tile * 64 + lane;
    const int px4c = min(px4, P4_N - 1);
    const float* xp = x + ((size_t)a * C_N + cg * 64 + wid) * P_N + (size_t)px4c * 4;

#define LD(k) const float4 v##k = *reinterpret_cast<const float4*>(xp + (size_t)(4 * (k)) * P_N);
    LD(0)  LD(1)  LD(2)  LD(3)  LD(4)  LD(5)  LD(6)  LD(7)
    LD(8)  LD(9)  LD(10) LD(11) LD(12) LD(13) LD(14) LD(15)
#undef LD

    const float4 cm4 = reinterpret_cast<const float4*>(s_cm)[lane];

    float4 acc[O_N];
    #pragma unroll
    for (int o = 0; o < O_N; ++o) acc[o] = make_float4(0.f, 0.f, 0.f, 0.f);

#define FMA(k)                                                                 \
    {                                                                          \
        float4 v = v##k;                                                       \
        v.x += cm4.x; v.y += cm4.y; v.z += cm4.z; v.w += cm4.w;                \
        const float* wc = s_w + (wid + 4 * (k)) * 8;   /* wave-uniform */      \
        const float4 wA = *reinterpret_cast<const float4*>(wc);                \
        const float4 wB = *reinterpret_cast<const float4*>(wc + 4);            \
        acc[0].x = fmaf(wA.x, v.x, acc[0].x); acc[0].y = fmaf(wA.x, v.y, acc[0].y); \
        acc[0].z = fmaf(wA.x, v.z, acc[0].z); acc[0].w = fmaf(wA.x, v.w, acc[0].w); \
        acc[1].x = fmaf(wA.y, v.x, acc[1].x); acc[1].y = fmaf(wA.y, v.y, acc[1].y); \
        acc[1].z = fmaf(wA.y, v.z, acc[1].z); acc[1].w = fmaf(wA.y, v.w, acc[1].w); \
        acc[2].x = fmaf(wA.z, v.x, acc[2].x); acc[2].y = fmaf(wA.z, v.y, acc[2].y); \
        acc[2].z = fmaf(wA.z, v.z, acc[2].z); acc[2].w = fmaf(wA.z, v.w, acc[2].w); \
        acc[3].x = fmaf(wA.w, v.x, acc[3].x); acc[3].y = fmaf(wA.w, v.y, acc[3].y); \
        acc[3].z = fmaf(wA.w, v.z, acc[3].z); acc[3].w = fmaf(wA.w, v.w, acc[3].w); \
        acc[4].x = fmaf(wB.x, v.x, acc[4].x); acc[4].y = fmaf(wB.x, v.y, acc[4].y); \
        acc[4].z = fmaf(wB.x, v.z, acc[4].z); acc[4].w = fmaf(wB.x, v.w, acc[4].w); \
        acc[5].x = fmaf(wB.y, v.x, acc[5].x); acc[5].y = fmaf(wB.y, v.y, acc[5].y); \
        acc[5].z = fmaf(wB.y, v.z, acc[5].z); acc[5].w = fmaf(wB.y, v.w, acc[5].w); \
        acc[6].x = fmaf(wB.z, v.x, acc[6].x); acc[6].y = fmaf(wB.z, v.y, acc[6].y); \
        acc[6].z = fmaf(wB.z, v.z, acc[6].z); acc[6].w = fmaf(wB.z, v.w, acc[6].w); \
    }
    FMA(0)  FMA(1)  FMA(2)  FMA(3)  FMA(4)  FMA(5)  FMA(6)  FMA(7)
    FMA(8)  FMA(9)  FMA(10) FMA(11) FMA(12) FMA(13) FMA(14) FMA(15)
#undef FMA

    // ---- cross-wave reduce (4 waves = 4 channel-interleaves) ----
    #pragma unroll
    for (int o = 0; o < O_N; ++o)
        s_red[o][wid][lane] = acc[o];
    __syncthreads();

    // 448 (px4, o) pairs over 256 threads, strided (r9 lesson)
    for (int pair = tid; pair < 64 * O_N; pair += 256) {
        const int pl = pair & 63;
        const int o  = pair >> 6;
        const int pg = tile * 64 + pl;
        if (pg >= P4_N) continue;
        const float4 s0 = s_red[o][0][pl];
        const float4 s1 = s_red[o][1][pl];
        const float4 s2 = s_red[o][2][pl];
        const float4 s3 = s_red[o][3][pl];
        float4 pv;
        pv.x = s0.x + s1.x + s2.x + s3.x;
        pv.y = s0.y + s1.y + s2.y + s3.y;
        pv.z = s0.z + s1.z + s2.z + s3.z;
        pv.w = s0.w + s1.w + s2.w + s3.w;
        reinterpret_cast<float4*>(part)[((size_t)(cg * A_N + a) * O_N + o) * P4_N + pg] = pv;
    }
}

// ---------------------------------------------------------------------------
// Finalize: z = sum_cg part[cg]; ssolo = sigmoid(z + b).
// Thread = (a*7+o, px4) pair: 120960 items, 473 blocks x 256.
// ---------------------------------------------------------------------------
__launch_bounds__(256)
__global__ void k_finalize(const float* __restrict__ part, const float* __restrict__ b,
                           float* __restrict__ z, float* __restrict__ ssolo)
{
    const int id = blockIdx.x * 256 + threadIdx.x;
    if (id >= A_N * O_N * P4_N) return;
    const int px4 = id % P4_N;
    const int ao  = id / P4_N;           // a*7+o, matches z/ssolo plane order
    const int o   = ao % O_N;

    const float4* p4 = reinterpret_cast<const float4*>(part);
    float4 s = p4[((size_t)(0 * A_N * O_N) + ao) * P4_N + px4];
    #pragma unroll
    for (int g = 1; g < NCG; ++g) {
        const float4 t = p4[((size_t)(g * A_N * O_N) + ao) * P4_N + px4];
        s.x += t.x; s.y += t.y; s.z += t.z; s.w += t.w;
    }
    reinterpret_cast<float4*>(z)[(size_t)ao * P4_N + px4] = s;
    const float bo = b[o];
    float4 sv;
    sv.x = sigmoidf_(s.x + bo);
    sv.y = sigmoidf_(s.y + bo);
    sv.z = sigmoidf_(s.z + bo);
    sv.w = sigmoidf_(s.w + bo);
    reinterpret_cast<float4*>(ssolo)[(size_t)ao * P4_N + px4] = sv;
}

// ---------------------------------------------------------------------------
// Aggregation: per ego i, pixel p: saggr = sigmoid(b + sum_j adj[i,j]!=0 ?
//              zero-padded-bilinear(z[j], rel[i,j] @ [u,v,1]) : 0)
// z planes total 1.9 MB — L2-resident gathers. 1080 blocks x 64.
// ---------------------------------------------------------------------------
__launch_bounds__(64)
__global__ void k_aggr(const float* __restrict__ z, const float* __restrict__ rel,
                       const int* __restrict__ adj, const float* __restrict__ b,
                       float* __restrict__ saggr)
{
    const int i = blockIdx.x / 135;
    const int p = (blockIdx.x - i * 135) * 64 + threadIdx.x;
    const int vy = p / W_N, ux = p - vy * W_N;
    const float fu = (float)ux, fv = (float)vy;

    float acc[O_N];
    #pragma unroll
    for (int o = 0; o < O_N; ++o) acc[o] = b[o];

    for (int j = 0; j < A_N; ++j) {
        if (adj[i * A_N + j] == 0) continue;
        const float* M = rel + (i * A_N + j) * 6;
        float sx = M[0] * fu + M[1] * fv + M[2];
        float sy = M[3] * fu + M[4] * fv + M[5];
        if (!(sx > -1.0f && sx < (float)W_N && sy > -1.0f && sy < (float)H_N)) continue;
        float x0f = floorf(sx), y0f = floorf(sy);
        float wx = sx - x0f, wy = sy - y0f;
        int x0 = (int)x0f, y0 = (int)y0f;
        int x1 = x0 + 1,  y1 = y0 + 1;
        float w00 = (1.0f - wy) * (1.0f - wx), w01 = (1.0f - wy) * wx;
        float w10 = wy * (1.0f - wx),          w11 = wy * wx;
        if (x0 < 0)    { w00 = 0.0f; w10 = 0.0f; x0 = 0; }
        if (x1 >= W_N) { w01 = 0.0f; w11 = 0.0f; x1 = W_N - 1; }
        if (y0 < 0)    { w00 = 0.0f; w01 = 0.0f; y0 = 0; }
        if (y1 >= H_N) { w10 = 0.0f; w11 = 0.0f; y1 = H_N - 1; }
        const int i00 = y0 * W_N + x0, i01 = y0 * W_N + x1;
        const int i10 = y1 * W_N + x0, i11 = y1 * W_N + x1;
        const float* zj = z + j * O_N * P_N;
        #pragma unroll
        for (int o = 0; o < O_N; ++o) {
            const float* zp = zj + o * P_N;
            acc[o] += w00 * zp[i00] + w01 * zp[i01] + w10 * zp[i10] + w11 * zp[i11];
        }
    }
    const int ob = i * O_N * P_N + p;
    #pragma unroll
    for (int o = 0; o < O_N; ++o) saggr[ob + o * P_N] = sigmoidf_(acc[o]);
}

// ---------------------------------------------------------------------------
// Upsample: align_corners=True bilinear 80x108 -> 256x256, f32 out.
// 4 px/thread -> float4 stores; 7168 blocks x 256 exact.
// Output layout: [solo(8,7,256,256), aggr(8,7,256,256)] flat f32.
// ---------------------------------------------------------------------------
__launch_bounds__(256)
__global__ void k_upsample(const float* __restrict__ ssolo, const float* __restrict__ saggr,
                           float* __restrict__ out)
{
    const int idx = blockIdx.x * 256 + threadIdx.x;   // quad index
    int k = idx;
    const int oxq = k & 63;   k >>= 6;
    const int oy  = k & 255;  k >>= 8;
    const int o   = k % O_N;  k /= O_N;
    const int a   = k & 7;    k >>= 3;
    const int t   = k;        // 0 = solo, 1 = aggr

    const float* src = (t == 0 ? ssolo : saggr) + (a * O_N + o) * P_N;
    float syf = (float)oy * (79.0f / 255.0f);
    int y0 = (int)syf; y0 = min(y0, H_N - 2);
    float wy = syf - (float)y0;
    const float* r0 = src + y0 * W_N;
    const float* r1 = r0 + W_N;

    float res[4];
    #pragma unroll
    for (int q = 0; q < 4; ++q) {
        int ox = oxq * 4 + q;
        float sxf = (float)ox * (107.0f / 255.0f);
        int x0 = (int)sxf; x0 = min(x0, W_N - 2);
        float wx = sxf - (float)x0;
        float c0 = r0[x0]     * (1.0f - wy) + r1[x0]     * wy;
        float c1 = r0[x0 + 1] * (1.0f - wy) + r1[x0 + 1] * wy;
        res[q] = c0 * (1.0f - wx) + c1 * wx;
    }
    *reinterpret_cast<float4*>(out + (size_t)idx * 4) =
        make_float4(res[0], res[1], res[2], res[3]);
}

// ---------------------------------------------------------------------------
extern "C" void kernel_launch(void* const* d_in, const int* in_sizes, int n_in,
                              void* d_out, int out_size, void* d_ws, size_t ws_size,
                              hipStream_t stream)
{
    (void)in_sizes; (void)n_in; (void)out_size; (void)ws_size;
    const float* x    = (const float*)d_in[0];
    const float* rel  = (const float*)d_in[1];
    const int*   adj  = (const int*)d_in[2];
    const float* cmsk = (const float*)d_in[3];
    const float* wcls = (const float*)d_in[4];
    const float* bcls = (const float*)d_in[5];
    float* out = (float*)d_out;   // reference output dtype is float32

    float* ws    = (float*)d_ws;
    float* part  = ws;                          // 4*8*7*8640 = 1,935,360 f32 (7.7 MB)
    float* z     = part  + NCG * A_N * O_N * P_N;
    float* ssolo = z     + A_N * O_N * P_N;
    float* saggr = ssolo + A_N * O_N * P_N;     // total ~13.6 MB

    k_convp   <<<A_N * TPA * NCG, 256, 0, stream>>>(x, cmsk, wcls, part);
    k_finalize<<<(A_N * O_N * P4_N + 255) / 256, 256, 0, stream>>>(part, bcls, z, ssolo);
    k_aggr    <<<1080, 64, 0, stream>>>(z, rel, adj, bcls, saggr);
    k_upsample<<<7168, 256, 0, stream>>>(ssolo, saggr, out);
}